// Round 10
// baseline (291.446 us; speedup 1.0000x reference)
//
#include <hip/hip_runtime.h>
#include <math.h>

typedef unsigned short u16;
typedef __attribute__((ext_vector_type(4))) float f32x4;
typedef __attribute__((ext_vector_type(16))) float f32x16;
typedef __attribute__((ext_vector_type(4))) unsigned short u16x4;
typedef __attribute__((ext_vector_type(8))) short bf16x8;
typedef __attribute__((ext_vector_type(8))) unsigned short u16x8;

#define LOG2E 1.4426950408889634f
#define QSCALE (0.08838834764831845f * LOG2E)   // 1/sqrt(128) * log2(e)

__device__ __forceinline__ u16 f2bf(float f) {
  union { float f; unsigned u; } v; v.f = f;
  unsigned r = (v.u + 0x7fff + ((v.u >> 16) & 1)) >> 16;
  return (u16)r;
}
__device__ __forceinline__ float bf2f(u16 u) {
  union { unsigned u; float f; } v; v.u = ((unsigned)u) << 16; return v.f;
}
__device__ __forceinline__ void stor(float* C, size_t i, float v) { C[i] = v; }
__device__ __forceinline__ void stor(u16* C, size_t i, float v) { C[i] = f2bf(v); }

// packed f32x2 -> bf16x2 (dst.lo = bf16(a), dst.hi = bf16(b))
__device__ __forceinline__ unsigned cvtpk(float a, float b) {
  unsigned r;
  asm("v_cvt_pk_bf16_f32 %0, %1, %2" : "=v"(r) : "v"(a), "v"(b));
  return r;
}
// swap: a.hi-lanes <-> b.lo-lanes.
__device__ __forceinline__ void plswap(unsigned &a, unsigned &b) {
  asm volatile("v_permlane32_swap_b32 %0, %1" : "+v"(a), "+v"(b));
}

// ---------------------------------------------------------------------------
// f32 -> bf16 conversion, 4 elems/thread.
// ---------------------------------------------------------------------------
__global__ void conv_f32_bf16(const float* __restrict__ src, u16* __restrict__ dst) {
  int i = (blockIdx.x * blockDim.x + threadIdx.x) * 4;
  f32x4 v = *(const f32x4*)(src + i);
  u16x4 o;
#pragma unroll
  for (int j = 0; j < 4; ++j) o[j] = f2bf(v[j]);
  *(u16x4*)(dst + i) = o;
}

// ---------------------------------------------------------------------------
// GEMM: C (MxN, TOUT row-major) = A (MxK bf16 row-major) * B^T (B: NxK bf16)
// m97 structure: 128x128 tile, BK=32, 4 waves (2x2), 4x4 16x16x32 frags/wave.
// ---------------------------------------------------------------------------
template <typename TOUT>
__global__ __launch_bounds__(256)
void gemm_bt(const u16* __restrict__ A, const u16* __restrict__ B,
             TOUT* __restrict__ C, int M, int N, int K) {
  __shared__ u16 lds_a[128 * 32];
  __shared__ u16 lds_b[128 * 32];
  const int tid  = threadIdx.x;
  const int lane = tid & 63;
  const int wid  = tid >> 6;
  const int wr = wid >> 1, wc = wid & 1;
  const int fr = lane & 15, fq = lane >> 4;
  const int row0 = blockIdx.x * 128, col0 = blockIdx.y * 128;
  const u16* ga = A + (size_t)row0 * K;
  const u16* gb = B + (size_t)col0 * K;
  f32x4 acc[4][4] = {};
  const int toff = tid * 16;

  for (int k0 = 0; k0 < K; k0 += 32) {
#pragma unroll
    for (int i = 0; i < 2; ++i) {
      int off = i * 4096 + toff;
      int rr  = off >> 6;
      int cb  = off & 63;
      __builtin_amdgcn_global_load_lds(
          (const __attribute__((address_space(1))) void*)((const char*)(ga + (size_t)rr * K + k0) + cb),
          (__attribute__((address_space(3))) void*)((char*)lds_a + off), 16, 0, 0);
      __builtin_amdgcn_global_load_lds(
          (const __attribute__((address_space(1))) void*)((const char*)(gb + (size_t)rr * K + k0) + cb),
          (__attribute__((address_space(3))) void*)((char*)lds_b + off), 16, 0, 0);
    }
    __syncthreads();
    bf16x8 af[4], bfv[4];
#pragma unroll
    for (int m = 0; m < 4; ++m)
      af[m] = *(const bf16x8*)&lds_a[(wr * 64 + m * 16 + fr) * 32 + fq * 8];
#pragma unroll
    for (int n = 0; n < 4; ++n)
      bfv[n] = *(const bf16x8*)&lds_b[(wc * 64 + n * 16 + fr) * 32 + fq * 8];
#pragma unroll
    for (int m = 0; m < 4; ++m)
#pragma unroll
      for (int n = 0; n < 4; ++n)
        acc[m][n] = __builtin_amdgcn_mfma_f32_16x16x32_bf16(af[m], bfv[n], acc[m][n], 0, 0, 0);
    __syncthreads();
  }

#pragma unroll
  for (int m = 0; m < 4; ++m)
#pragma unroll
    for (int n = 0; n < 4; ++n) {
      int row = row0 + wr * 64 + m * 16 + fq * 4;
      int col = col0 + wc * 64 + n * 16 + fr;
#pragma unroll
      for (int r = 0; r < 4; ++r)
        stor(C, (size_t)(row + r) * N + col, acc[m][n][r]);
    }
}

// ---------------------------------------------------------------------------
// RoPE in-place on q,k parts of qkv. Q additionally scaled by QSCALE
// (softmax scale folded in; k,v untouched).
// ---------------------------------------------------------------------------
__global__ void rope_qk(u16* qkv) {
  int idx = blockIdx.x * blockDim.x + threadIdx.x;
  int i4 = idx & 15;
  int h  = (idx >> 4) & 15;
  int t  = (idx >> 8) & 1;
  int s  = idx >> 9;
  u16* p = qkv + (size_t)s * 6144 + t * 2048 + h * 128 + i4 * 8;
  const float post = t ? 1.0f : QSCALE;
  u16x8 v = *(const u16x8*)p;
  u16x8 w;
#pragma unroll
  for (int j = 0; j < 4; ++j) {
    int i = i4 * 4 + j;
    float inv = exp2f(-(float)i * 0.2076205059304601f);  // 10000^(-i/64)
    float ang = (float)s * inv;
    float sn, cs;
    sincosf(ang, &sn, &cs);
    float e = bf2f(v[2 * j]);
    float o = bf2f(v[2 * j + 1]);
    w[2 * j]     = f2bf((e * cs - o * sn) * post);
    w[2 * j + 1] = f2bf((e * sn + o * cs) * post);
  }
  *(u16x8*)p = w;
}

// ---------------------------------------------------------------------------
// Transpose V: vt[(h*128+d)][s] = qkv[s][4096 + h*128 + d]
// ---------------------------------------------------------------------------
__global__ void transpose_v(const u16* __restrict__ qkv, u16* __restrict__ vt) {
  __shared__ u16 tile[32][33];
  int s0 = blockIdx.x * 32, c0 = blockIdx.y * 32;
  int tx = threadIdx.x & 31, ty = threadIdx.x >> 5;  // 32 x 8
#pragma unroll
  for (int i = ty; i < 32; i += 8)
    tile[i][tx] = qkv[(size_t)(s0 + i) * 6144 + 4096 + c0 + tx];
  __syncthreads();
#pragma unroll
  for (int i = ty; i < 32; i += 8)
    vt[(size_t)(c0 + i) * 2048 + s0 + tx] = tile[tx][i];
}

// ---------------------------------------------------------------------------
// Causal flash attention, split-KV, 32x32 MFMA, swapped QK^T.
// Block = 256 thr (4 waves) = ONE q-tile x 4 kv-split waves (t==ksel mod 4).
// grid = (64 q-tiles, 16 heads). Q frags hoisted (loop-invariant, pre-scaled
// in rope). S = mfma(K,Q): S[kv][q], q = lane&31. P -> PV A-frags via
// v_cvt_pk_bf16_f32 + v_permlane32_swap_b32. T13 defer-max (THR=8, log2).
// Flash-merge across the 4 waves via LDS.
// ---------------------------------------------------------------------------
__global__ __launch_bounds__(256)
void attn_fwd(const u16* __restrict__ qkv, const u16* __restrict__ vt,
              u16* __restrict__ ao) {
  const int h    = blockIdx.y;
  const int tid  = threadIdx.x;
  const int lane = tid & 63;
  const int ksel = tid >> 6;       // 0..3 kv-split slot
  const int l31  = lane & 31;
  const int hh   = lane >> 5;
  const int tile = blockIdx.x;
  const int q0 = tile * 32;
  const u16* Qb = qkv + h * 128;
  const u16* Kb = qkv + 2048 + h * 128;
  const u16* Vb = vt + (size_t)h * 128 * 2048;

  __shared__ float Obuf[32][128];   // 16 KB (merge phase)
  __shared__ float mls[4][32][2];   // per-wave (m, l) per q-row

  // hoisted Q fragments (pre-scaled by QSCALE in rope); qf[s] = head-dim slice s
  const size_t qrow = (size_t)(q0 + l31) * 6144;
  bf16x8 qf[8];
#pragma unroll
  for (int s = 0; s < 8; ++s)
    qf[s] = *(const bf16x8*)&Qb[qrow + s * 16 + hh * 8];

  f32x16 oacc[4] = {};              // [d-chunk]; q=(r&3)+8*(r>>2)+4*hh, d=32c+l31
  float M = -1e30f, L = 0.f;

  for (int t = ksel; t <= tile; t += 4) {
    const int kv0 = t * 32;
    const size_t krow = (size_t)(kv0 + l31) * 6144;

    // V fragments first (independent; latency hides under QK^T MFMAs)
    bf16x8 vf[4][2];
#pragma unroll
    for (int c = 0; c < 4; ++c)
#pragma unroll
      for (int tt = 0; tt < 2; ++tt)
        vf[c][tt] = *(const bf16x8*)&Vb[(size_t)(32 * c + l31) * 2048 + kv0 + tt * 16 + hh * 8];

    // QK^T swapped: A = K rows, B = Q rows (hoisted); two 4-slice batches
    f32x16 sc = {};
    {
      bf16x8 kf[4];
#pragma unroll
      for (int s = 0; s < 4; ++s)
        kf[s] = *(const bf16x8*)&Kb[krow + s * 16 + hh * 8];
#pragma unroll
      for (int s = 0; s < 4; ++s)
        sc = __builtin_amdgcn_mfma_f32_32x32x16_bf16(kf[s], qf[s], sc, 0, 0, 0);
#pragma unroll
      for (int s = 0; s < 4; ++s)
        kf[s] = *(const bf16x8*)&Kb[krow + (s + 4) * 16 + hh * 8];
#pragma unroll
      for (int s = 0; s < 4; ++s)
        sc = __builtin_amdgcn_mfma_f32_32x32x16_bf16(kf[s], qf[s + 4], sc, 0, 0, 0);  // FIX: was qf[s]
    }

    // causal mask on the diagonal tile (S[kv][q]: q=l31, kv=(r&3)+8(r>>2)+4hh)
    if (t == tile) {
#pragma unroll
      for (int r = 0; r < 16; ++r) {
        int kv = (r & 3) + 8 * (r >> 2) + 4 * hh;
        if (kv > l31) sc[r] = -1e30f;
      }
    }

    // per-lane (per-q) online softmax, T13 defer-max
    float pm = fmaxf(fmaxf(fmaxf(sc[0], sc[1]), fmaxf(sc[2], sc[3])),
                     fmaxf(fmaxf(sc[4], sc[5]), fmaxf(sc[6], sc[7])));
    float pm2 = fmaxf(fmaxf(fmaxf(sc[8], sc[9]), fmaxf(sc[10], sc[11])),
                      fmaxf(fmaxf(sc[12], sc[13]), fmaxf(sc[14], sc[15])));
    pm = fmaxf(pm, pm2);
    pm = fmaxf(pm, __shfl_xor(pm, 32, 64));

    bool defer = (pm <= M + 8.0f);
    if (!__all(defer)) {
      float Mn = fmaxf(M, pm);
      float corr = exp2f(M - Mn);
      M = Mn;
      L *= corr;
#pragma unroll
      for (int r = 0; r < 16; ++r) {
        float cr = __shfl(corr, (r & 3) + 8 * (r >> 2) + 4 * hh, 64);
#pragma unroll
        for (int c = 0; c < 4; ++c) oacc[c][r] *= cr;
      }
    }

#pragma unroll
    for (int r = 0; r < 16; ++r) sc[r] = exp2f(sc[r] - M);
    float rs = ((sc[0] + sc[1]) + (sc[2] + sc[3])) + ((sc[4] + sc[5]) + (sc[6] + sc[7]))
             + ((sc[8] + sc[9]) + (sc[10] + sc[11])) + ((sc[12] + sc[13]) + (sc[14] + sc[15]));
    rs += __shfl_xor(rs, 32, 64);
    L += rs;

    // pack P into PV A-frags and accumulate O
#pragma unroll
    for (int tt = 0; tt < 2; ++tt) {
      unsigned A0 = cvtpk(sc[8 * tt + 0], sc[8 * tt + 1]);
      unsigned A1 = cvtpk(sc[8 * tt + 2], sc[8 * tt + 3]);
      unsigned B0 = cvtpk(sc[8 * tt + 4], sc[8 * tt + 5]);
      unsigned B1 = cvtpk(sc[8 * tt + 6], sc[8 * tt + 7]);
      plswap(A0, B0);
      plswap(A1, B1);
      union { unsigned w[4]; bf16x8 v; } pa;
      pa.w[0] = A0; pa.w[1] = A1; pa.w[2] = B0; pa.w[3] = B1;
#pragma unroll
      for (int c = 0; c < 4; ++c)
        oacc[c] = __builtin_amdgcn_mfma_f32_32x32x16_bf16(pa.v, vf[c][tt], oacc[c], 0, 0, 0);
    }
  }

  // ---- flash merge across the 4 kv-split waves ----
  if (hh == 0) { mls[ksel][l31][0] = M; mls[ksel][l31][1] = L; }
  __syncthreads();

  for (int w = 0; w < 4; ++w) {
    if (ksel == w) {
#pragma unroll
      for (int r = 0; r < 16; ++r) {
        int q = (r & 3) + 8 * (r >> 2) + 4 * hh;
        float m_own = mls[ksel][q][0];
        float Mg = fmaxf(fmaxf(mls[0][q][0], mls[1][q][0]),
                         fmaxf(mls[2][q][0], mls[3][q][0]));
        float s = exp2f(m_own - Mg);
#pragma unroll
        for (int c = 0; c < 4; ++c) {
          float v = oacc[c][r] * s;
          if (w == 0) Obuf[q][32 * c + l31] = v;
          else        Obuf[q][32 * c + l31] += v;
        }
      }
    }
    __syncthreads();
  }

  // write-out: wave ksel normalizes+stores rows ksel*8 .. ksel*8+7
#pragma unroll
  for (int rr = 0; rr < 8; ++rr) {
    int row = ksel * 8 + rr;
    float Mg = fmaxf(fmaxf(mls[0][row][0], mls[1][row][0]),
                     fmaxf(mls[2][row][0], mls[3][row][0]));
    float lt = 0.f;
#pragma unroll
    for (int w2 = 0; w2 < 4; ++w2)
      lt += exp2f(mls[w2][row][0] - Mg) * mls[w2][row][1];
    float inv = 1.0f / lt;
    float v0 = Obuf[row][lane * 2]     * inv;
    float v1 = Obuf[row][lane * 2 + 1] * inv;
    unsigned pack = (unsigned)f2bf(v0) | ((unsigned)f2bf(v1) << 16);
    *(unsigned*)&ao[(size_t)(q0 + row) * 2048 + h * 128 + lane * 2] = pack;
  }
}

// ---------------------------------------------------------------------------
extern "C" void kernel_launch(void* const* d_in, const int* in_sizes, int n_in,
                              void* d_out, int out_size, void* d_ws, size_t ws_size,
                              hipStream_t stream) {
  const float* x     = (const float*)d_in[0];   // 2048 x 2048 f32
  const float* w_qkv = (const float*)d_in[1];   // 6144 x 2048 f32
  const float* w_out = (const float*)d_in[2];   // 2048 x 2048 f32
  float* out = (float*)d_out;                   // 2048 x 2048 f32
  const int S = 2048, H = 2048, O3 = 6144;

  // workspace (u16 elems), peak 58.8 MB with aliasing:
  u16* qkv     = (u16*)d_ws;                    // S*O3 = 25.2 MB
  u16* x_bf    = qkv + (size_t)S * O3;          //  8.4 MB
  u16* wqkv_bf = x_bf + (size_t)S * H;          // 25.2 MB
  u16* ao      = x_bf;                          // alias (x_bf dead after GEMM1)
  u16* vt      = wqkv_bf;                       // alias (wqkv_bf dead after GEMM1)
  u16* wout_bf = wqkv_bf + (size_t)H * S;       // alias, fits in wqkv_bf region

  // 1. convert inputs to bf16
  conv_f32_bf16<<<(S * H) / 1024, 256, 0, stream>>>(x, x_bf);
  conv_f32_bf16<<<(O3 * H) / 1024, 256, 0, stream>>>(w_qkv, wqkv_bf);
  // 2. qkv = x @ w_qkv^T   (M=2048, N=6144, K=2048)
  gemm_bt<u16><<<dim3(S / 128, O3 / 128), 256, 0, stream>>>(x_bf, wqkv_bf, qkv, S, O3, H);
  // 3. RoPE on q,k in place (q pre-scaled by QSCALE)
  rope_qk<<<(S * 2 * 16 * 16) / 256, 256, 0, stream>>>(qkv);
  // 4. vt[h*128+d][s] = V   (into region freed after GEMM1)
  transpose_v<<<dim3(S / 32, H / 32), 256, 0, stream>>>(qkv, vt);
  // 5. convert w_out
  conv_f32_bf16<<<(S * H) / 1024, 256, 0, stream>>>(w_out, wout_bf);
  // 6. causal flash attention (split-KV, 1 q-tile/block) -> ao[s][h*128+d]
  attn_fwd<<<dim3(64, 16), 256, 0, stream>>>(qkv, vt, ao);
  // 7. out = ao @ w_out^T  (M=2048, N=2048, K=2048), f32 store
  gemm_bt<float><<<dim3(S / 128, H / 128), 256, 0, stream>>>(ao, wout_bf, out, S, H, H);
}

// Round 11
// 245.032 us; speedup vs baseline: 1.1894x; 1.1894x over previous
//
#include <hip/hip_runtime.h>
#include <math.h>

typedef unsigned short u16;
typedef __attribute__((ext_vector_type(4))) float f32x4;
typedef __attribute__((ext_vector_type(16))) float f32x16;
typedef __attribute__((ext_vector_type(4))) unsigned short u16x4;
typedef __attribute__((ext_vector_type(8))) short bf16x8;
typedef __attribute__((ext_vector_type(8))) unsigned short u16x8;

#define LOG2E 1.4426950408889634f
#define QSCALE (0.08838834764831845f * LOG2E)   // 1/sqrt(128) * log2(e)

__device__ __forceinline__ u16 f2bf(float f) {
  union { float f; unsigned u; } v; v.f = f;
  unsigned r = (v.u + 0x7fff + ((v.u >> 16) & 1)) >> 16;
  return (u16)r;
}
__device__ __forceinline__ float bf2f(u16 u) {
  union { unsigned u; float f; } v; v.u = ((unsigned)u) << 16; return v.f;
}
__device__ __forceinline__ void stor(float* C, size_t i, float v) { C[i] = v; }
__device__ __forceinline__ void stor(u16* C, size_t i, float v) { C[i] = f2bf(v); }

// packed f32x2 -> bf16x2 (dst.lo = bf16(a), dst.hi = bf16(b))
__device__ __forceinline__ unsigned cvtpk(float a, float b) {
  unsigned r;
  asm("v_cvt_pk_bf16_f32 %0, %1, %2" : "=v"(r) : "v"(a), "v"(b));
  return r;
}
// swap: a.hi-lanes <-> b.lo-lanes.
__device__ __forceinline__ void plswap(unsigned &a, unsigned &b) {
  asm volatile("v_permlane32_swap_b32 %0, %1" : "+v"(a), "+v"(b));
}

// ---------------------------------------------------------------------------
// f32 -> bf16 conversion, 4 elems/thread.
// ---------------------------------------------------------------------------
__global__ void conv_f32_bf16(const float* __restrict__ src, u16* __restrict__ dst) {
  int i = (blockIdx.x * blockDim.x + threadIdx.x) * 4;
  f32x4 v = *(const f32x4*)(src + i);
  u16x4 o;
#pragma unroll
  for (int j = 0; j < 4; ++j) o[j] = f2bf(v[j]);
  *(u16x4*)(dst + i) = o;
}

// ---------------------------------------------------------------------------
// GEMM: C (MxN, TOUT row-major) = A (MxK bf16 row-major) * B^T (B: NxK bf16)
// m97 structure: 128x128 tile, BK=32, 4 waves (2x2), 4x4 16x16x32 frags/wave.
// ---------------------------------------------------------------------------
template <typename TOUT>
__global__ __launch_bounds__(256)
void gemm_bt(const u16* __restrict__ A, const u16* __restrict__ B,
             TOUT* __restrict__ C, int M, int N, int K) {
  __shared__ u16 lds_a[128 * 32];
  __shared__ u16 lds_b[128 * 32];
  const int tid  = threadIdx.x;
  const int lane = tid & 63;
  const int wid  = tid >> 6;
  const int wr = wid >> 1, wc = wid & 1;
  const int fr = lane & 15, fq = lane >> 4;
  const int row0 = blockIdx.x * 128, col0 = blockIdx.y * 128;
  const u16* ga = A + (size_t)row0 * K;
  const u16* gb = B + (size_t)col0 * K;
  f32x4 acc[4][4] = {};
  const int toff = tid * 16;

  for (int k0 = 0; k0 < K; k0 += 32) {
#pragma unroll
    for (int i = 0; i < 2; ++i) {
      int off = i * 4096 + toff;
      int rr  = off >> 6;
      int cb  = off & 63;
      __builtin_amdgcn_global_load_lds(
          (const __attribute__((address_space(1))) void*)((const char*)(ga + (size_t)rr * K + k0) + cb),
          (__attribute__((address_space(3))) void*)((char*)lds_a + off), 16, 0, 0);
      __builtin_amdgcn_global_load_lds(
          (const __attribute__((address_space(1))) void*)((const char*)(gb + (size_t)rr * K + k0) + cb),
          (__attribute__((address_space(3))) void*)((char*)lds_b + off), 16, 0, 0);
    }
    __syncthreads();
    bf16x8 af[4], bfv[4];
#pragma unroll
    for (int m = 0; m < 4; ++m)
      af[m] = *(const bf16x8*)&lds_a[(wr * 64 + m * 16 + fr) * 32 + fq * 8];
#pragma unroll
    for (int n = 0; n < 4; ++n)
      bfv[n] = *(const bf16x8*)&lds_b[(wc * 64 + n * 16 + fr) * 32 + fq * 8];
#pragma unroll
    for (int m = 0; m < 4; ++m)
#pragma unroll
      for (int n = 0; n < 4; ++n)
        acc[m][n] = __builtin_amdgcn_mfma_f32_16x16x32_bf16(af[m], bfv[n], acc[m][n], 0, 0, 0);
    __syncthreads();
  }

#pragma unroll
  for (int m = 0; m < 4; ++m)
#pragma unroll
    for (int n = 0; n < 4; ++n) {
      int row = row0 + wr * 64 + m * 16 + fq * 4;
      int col = col0 + wc * 64 + n * 16 + fr;
#pragma unroll
      for (int r = 0; r < 4; ++r)
        stor(C, (size_t)(row + r) * N + col, acc[m][n][r]);
    }
}

// ---------------------------------------------------------------------------
// RoPE in-place on q,k parts of qkv. Q additionally scaled by QSCALE
// (softmax scale folded in; k,v untouched).
// ---------------------------------------------------------------------------
__global__ void rope_qk(u16* qkv) {
  int idx = blockIdx.x * blockDim.x + threadIdx.x;
  int i4 = idx & 15;
  int h  = (idx >> 4) & 15;
  int t  = (idx >> 8) & 1;
  int s  = idx >> 9;
  u16* p = qkv + (size_t)s * 6144 + t * 2048 + h * 128 + i4 * 8;
  const float post = t ? 1.0f : QSCALE;
  u16x8 v = *(const u16x8*)p;
  u16x8 w;
#pragma unroll
  for (int j = 0; j < 4; ++j) {
    int i = i4 * 4 + j;
    float inv = exp2f(-(float)i * 0.2076205059304601f);  // 10000^(-i/64)
    float ang = (float)s * inv;
    float sn, cs;
    sincosf(ang, &sn, &cs);
    float e = bf2f(v[2 * j]);
    float o = bf2f(v[2 * j + 1]);
    w[2 * j]     = f2bf((e * cs - o * sn) * post);
    w[2 * j + 1] = f2bf((e * sn + o * cs) * post);
  }
  *(u16x8*)p = w;
}

// ---------------------------------------------------------------------------
// Transpose V: vt[(h*128+d)][s] = qkv[s][4096 + h*128 + d]
// ---------------------------------------------------------------------------
__global__ void transpose_v(const u16* __restrict__ qkv, u16* __restrict__ vt) {
  __shared__ u16 tile[32][33];
  int s0 = blockIdx.x * 32, c0 = blockIdx.y * 32;
  int tx = threadIdx.x & 31, ty = threadIdx.x >> 5;  // 32 x 8
#pragma unroll
  for (int i = ty; i < 32; i += 8)
    tile[i][tx] = qkv[(size_t)(s0 + i) * 6144 + 4096 + c0 + tx];
  __syncthreads();
#pragma unroll
  for (int i = ty; i < 32; i += 8)
    vt[(size_t)(c0 + i) * 2048 + s0 + tx] = tile[tx][i];
}

// ---------------------------------------------------------------------------
// Causal flash attention, split-KV, 32x32 MFMA, swapped QK^T.
// R8 paired frame: block = 512 thr (8 waves) = 2 q-tiles (blockIdx.x and
// 63-blockIdx.x; balanced 65 kv-tiles/block) x 4 kv-split waves (t==ksel%4).
// grid = (32, 16 heads). Q reloaded per-iter (keeps VGPR ~100 -> 2 blocks/CU).
// S = mfma(K,Q): S[kv][q], q=lane&31; per-lane softmax. P -> PV A-frags via
// v_cvt_pk_bf16_f32 + v_permlane32_swap_b32. T13 defer-max, T5 setprio.
// ---------------------------------------------------------------------------
__global__ __launch_bounds__(512)
void attn_fwd(const u16* __restrict__ qkv, const u16* __restrict__ vt,
              u16* __restrict__ ao) {
  const int h    = blockIdx.y;
  const int tid  = threadIdx.x;
  const int lane = tid & 63;
  const int wid  = tid >> 6;       // 0..7
  const int qsel = wid >> 2;       // which q-tile
  const int ksel = wid & 3;        // kv-split slot
  const int l31  = lane & 31;
  const int hh   = lane >> 5;
  const int tile = qsel ? 63 - (int)blockIdx.x : (int)blockIdx.x;
  const int q0 = tile * 32;
  const u16* Qb = qkv + h * 128;
  const u16* Kb = qkv + 2048 + h * 128;
  const u16* Vb = vt + (size_t)h * 128 * 2048;

  __shared__ float Obuf[2][32][128];   // 32 KB (merge phase)
  __shared__ float mls[2][4][32][2];   // per-wave (m, l) per q-row

  f32x16 oacc[4] = {};                 // q=(r&3)+8*(r>>2)+4*hh, d=32c+l31
  float M = -1e30f, L = 0.f;
  const size_t qrow = (size_t)(q0 + l31) * 6144;

  for (int t = ksel; t <= tile; t += 4) {
    const int kv0 = t * 32;
    const size_t krow = (size_t)(kv0 + l31) * 6144;

    // V fragments first (consumed last -> max latency overlap)
    bf16x8 vf[4][2];
#pragma unroll
    for (int c = 0; c < 4; ++c)
#pragma unroll
      for (int tt = 0; tt < 2; ++tt)
        vf[c][tt] = *(const bf16x8*)&Vb[(size_t)(32 * c + l31) * 2048 + kv0 + tt * 16 + hh * 8];

    // QK^T swapped: A = K rows, B = Q rows; 2 batches of 4 slices, regs reused
    f32x16 sc = {};
    {
      bf16x8 kf[4], qf[4];
#pragma unroll
      for (int s = 0; s < 4; ++s) {
        kf[s] = *(const bf16x8*)&Kb[krow + s * 16 + hh * 8];
        qf[s] = *(const bf16x8*)&Qb[qrow + s * 16 + hh * 8];
      }
      __builtin_amdgcn_s_setprio(1);
#pragma unroll
      for (int s = 0; s < 4; ++s)
        sc = __builtin_amdgcn_mfma_f32_32x32x16_bf16(kf[s], qf[s], sc, 0, 0, 0);
      __builtin_amdgcn_s_setprio(0);
#pragma unroll
      for (int s = 0; s < 4; ++s) {
        kf[s] = *(const bf16x8*)&Kb[krow + (s + 4) * 16 + hh * 8];
        qf[s] = *(const bf16x8*)&Qb[qrow + (s + 4) * 16 + hh * 8];
      }
      __builtin_amdgcn_s_setprio(1);
#pragma unroll
      for (int s = 0; s < 4; ++s)
        sc = __builtin_amdgcn_mfma_f32_32x32x16_bf16(kf[s], qf[s], sc, 0, 0, 0);
      __builtin_amdgcn_s_setprio(0);
    }

    // causal mask on the diagonal tile (S[kv][q]: q=l31, kv=(r&3)+8(r>>2)+4hh)
    if (t == tile) {
#pragma unroll
      for (int r = 0; r < 16; ++r) {
        int kv = (r & 3) + 8 * (r >> 2) + 4 * hh;
        if (kv > l31) sc[r] = -1e30f;
      }
    }

    // per-lane (per-q) online softmax, T13 defer-max
    float pm = fmaxf(fmaxf(fmaxf(sc[0], sc[1]), fmaxf(sc[2], sc[3])),
                     fmaxf(fmaxf(sc[4], sc[5]), fmaxf(sc[6], sc[7])));
    float pm2 = fmaxf(fmaxf(fmaxf(sc[8], sc[9]), fmaxf(sc[10], sc[11])),
                      fmaxf(fmaxf(sc[12], sc[13]), fmaxf(sc[14], sc[15])));
    pm = fmaxf(pm, pm2);
    pm = fmaxf(pm, __shfl_xor(pm, 32, 64));

    bool defer = (pm <= M + 8.0f);
    if (!__all(defer)) {
      float Mn = fmaxf(M, pm);
      float corr = exp2f(M - Mn);
      M = Mn;
      L *= corr;
#pragma unroll
      for (int r = 0; r < 16; ++r) {
        float cr = __shfl(corr, (r & 3) + 8 * (r >> 2) + 4 * hh, 64);
#pragma unroll
        for (int c = 0; c < 4; ++c) oacc[c][r] *= cr;
      }
    }

#pragma unroll
    for (int r = 0; r < 16; ++r) sc[r] = exp2f(sc[r] - M);
    float rs = ((sc[0] + sc[1]) + (sc[2] + sc[3])) + ((sc[4] + sc[5]) + (sc[6] + sc[7]))
             + ((sc[8] + sc[9]) + (sc[10] + sc[11])) + ((sc[12] + sc[13]) + (sc[14] + sc[15]));
    rs += __shfl_xor(rs, 32, 64);
    L += rs;

    // pack P into PV A-frags and accumulate O
#pragma unroll
    for (int tt = 0; tt < 2; ++tt) {
      unsigned A0 = cvtpk(sc[8 * tt + 0], sc[8 * tt + 1]);
      unsigned A1 = cvtpk(sc[8 * tt + 2], sc[8 * tt + 3]);
      unsigned B0 = cvtpk(sc[8 * tt + 4], sc[8 * tt + 5]);
      unsigned B1 = cvtpk(sc[8 * tt + 6], sc[8 * tt + 7]);
      plswap(A0, B0);
      plswap(A1, B1);
      union { unsigned w[4]; bf16x8 v; } pa;
      pa.w[0] = A0; pa.w[1] = A1; pa.w[2] = B0; pa.w[3] = B1;
      __builtin_amdgcn_s_setprio(1);
#pragma unroll
      for (int c = 0; c < 4; ++c)
        oacc[c] = __builtin_amdgcn_mfma_f32_32x32x16_bf16(pa.v, vf[c][tt], oacc[c], 0, 0, 0);
      __builtin_amdgcn_s_setprio(0);
    }
  }

  // ---- flash merge across the 4 kv-split waves of each q-tile ----
  if (hh == 0) { mls[qsel][ksel][l31][0] = M; mls[qsel][ksel][l31][1] = L; }
  __syncthreads();

  for (int w = 0; w < 4; ++w) {
    if (ksel == w) {
#pragma unroll
      for (int r = 0; r < 16; ++r) {
        int q = (r & 3) + 8 * (r >> 2) + 4 * hh;
        float m_own = mls[qsel][ksel][q][0];
        float Mg = fmaxf(fmaxf(mls[qsel][0][q][0], mls[qsel][1][q][0]),
                         fmaxf(mls[qsel][2][q][0], mls[qsel][3][q][0]));
        float s = exp2f(m_own - Mg);
#pragma unroll
        for (int c = 0; c < 4; ++c) {
          float v = oacc[c][r] * s;
          if (w == 0) Obuf[qsel][q][32 * c + l31] = v;
          else        Obuf[qsel][q][32 * c + l31] += v;
        }
      }
    }
    __syncthreads();
  }

  // write-out: wave (qsel,ksel) normalizes+stores rows ksel*8 .. ksel*8+7
#pragma unroll
  for (int rr = 0; rr < 8; ++rr) {
    int row = ksel * 8 + rr;
    float Mg = fmaxf(fmaxf(mls[qsel][0][row][0], mls[qsel][1][row][0]),
                     fmaxf(mls[qsel][2][row][0], mls[qsel][3][row][0]));
    float lt = 0.f;
#pragma unroll
    for (int w2 = 0; w2 < 4; ++w2)
      lt += exp2f(mls[qsel][w2][row][0] - Mg) * mls[qsel][w2][row][1];
    float inv = 1.0f / lt;
    float v0 = Obuf[qsel][row][lane * 2]     * inv;
    float v1 = Obuf[qsel][row][lane * 2 + 1] * inv;
    unsigned pack = (unsigned)f2bf(v0) | ((unsigned)f2bf(v1) << 16);
    *(unsigned*)&ao[(size_t)(q0 + row) * 2048 + h * 128 + lane * 2] = pack;
  }
}

// ---------------------------------------------------------------------------
extern "C" void kernel_launch(void* const* d_in, const int* in_sizes, int n_in,
                              void* d_out, int out_size, void* d_ws, size_t ws_size,
                              hipStream_t stream) {
  const float* x     = (const float*)d_in[0];   // 2048 x 2048 f32
  const float* w_qkv = (const float*)d_in[1];   // 6144 x 2048 f32
  const float* w_out = (const float*)d_in[2];   // 2048 x 2048 f32
  float* out = (float*)d_out;                   // 2048 x 2048 f32
  const int S = 2048, H = 2048, O3 = 6144;

  // workspace (u16 elems), peak 58.8 MB with aliasing:
  u16* qkv     = (u16*)d_ws;                    // S*O3 = 25.2 MB
  u16* x_bf    = qkv + (size_t)S * O3;          //  8.4 MB
  u16* wqkv_bf = x_bf + (size_t)S * H;          // 25.2 MB
  u16* ao      = x_bf;                          // alias (x_bf dead after GEMM1)
  u16* vt      = wqkv_bf;                       // alias (wqkv_bf dead after GEMM1)
  u16* wout_bf = wqkv_bf + (size_t)H * S;       // alias, fits in wqkv_bf region

  // 1. convert inputs to bf16
  conv_f32_bf16<<<(S * H) / 1024, 256, 0, stream>>>(x, x_bf);
  conv_f32_bf16<<<(O3 * H) / 1024, 256, 0, stream>>>(w_qkv, wqkv_bf);
  // 2. qkv = x @ w_qkv^T   (M=2048, N=6144, K=2048)
  gemm_bt<u16><<<dim3(S / 128, O3 / 128), 256, 0, stream>>>(x_bf, wqkv_bf, qkv, S, O3, H);
  // 3. RoPE on q,k in place (q pre-scaled by QSCALE)
  rope_qk<<<(S * 2 * 16 * 16) / 256, 256, 0, stream>>>(qkv);
  // 4. vt[h*128+d][s] = V   (into region freed after GEMM1)
  transpose_v<<<dim3(S / 32, H / 32), 256, 0, stream>>>(qkv, vt);
  // 5. convert w_out
  conv_f32_bf16<<<(S * H) / 1024, 256, 0, stream>>>(w_out, wout_bf);
  // 6. causal flash attention (paired split-KV) -> ao[s][h*128+d]
  attn_fwd<<<dim3(32, 16), 512, 0, stream>>>(qkv, vt, ao);
  // 7. out = ao @ w_out^T  (M=2048, N=2048, K=2048), f32 store
  gemm_bt<float><<<dim3(S / 128, H / 128), 256, 0, stream>>>(ao, wout_bf, out, S, H, H);
}

// Round 12
// 213.303 us; speedup vs baseline: 1.3663x; 1.1487x over previous
//
#include <hip/hip_runtime.h>
#include <math.h>

typedef unsigned short u16;
typedef __attribute__((ext_vector_type(4))) float f32x4;
typedef __attribute__((ext_vector_type(16))) float f32x16;
typedef __attribute__((ext_vector_type(4))) unsigned short u16x4;
typedef __attribute__((ext_vector_type(8))) short bf16x8;
typedef __attribute__((ext_vector_type(8))) unsigned short u16x8;

#define LOG2E 1.4426950408889634f
#define QSCALE (0.08838834764831845f * LOG2E)   // 1/sqrt(128) * log2(e)

__device__ __forceinline__ u16 f2bf(float f) {
  union { float f; unsigned u; } v; v.f = f;
  unsigned r = (v.u + 0x7fff + ((v.u >> 16) & 1)) >> 16;
  return (u16)r;
}
__device__ __forceinline__ float bf2f(u16 u) {
  union { unsigned u; float f; } v; v.u = ((unsigned)u) << 16; return v.f;
}
__device__ __forceinline__ void stor(float* C, size_t i, float v) { C[i] = v; }
__device__ __forceinline__ void stor(u16* C, size_t i, float v) { C[i] = f2bf(v); }

__device__ __forceinline__ unsigned cvtpk(float a, float b) {
  unsigned r;
  asm("v_cvt_pk_bf16_f32 %0, %1, %2" : "=v"(r) : "v"(a), "v"(b));
  return r;
}
__device__ __forceinline__ void plswap(unsigned &a, unsigned &b) {
  asm volatile("v_permlane32_swap_b32 %0, %1" : "+v"(a), "+v"(b));
}

// ---------------------------------------------------------------------------
// f32 -> bf16 conversion, 4 elems/thread.
// ---------------------------------------------------------------------------
__global__ void conv_f32_bf16(const float* __restrict__ src, u16* __restrict__ dst) {
  int i = (blockIdx.x * blockDim.x + threadIdx.x) * 4;
  f32x4 v = *(const f32x4*)(src + i);
  u16x4 o;
#pragma unroll
  for (int j = 0; j < 4; ++j) o[j] = f2bf(v[j]);
  *(u16x4*)(dst + i) = o;
}

// ---------------------------------------------------------------------------
// GEMM: C (MxN, TOUT row-major) = A (MxK bf16 row-major) * B^T (B: NxK bf16)
// m97 structure: 128x128 tile, BK=32, 4 waves (2x2), 4x4 16x16x32 frags/wave.
// ---------------------------------------------------------------------------
template <typename TOUT>
__global__ __launch_bounds__(256)
void gemm_bt(const u16* __restrict__ A, const u16* __restrict__ B,
             TOUT* __restrict__ C, int M, int N, int K) {
  __shared__ u16 lds_a[128 * 32];
  __shared__ u16 lds_b[128 * 32];
  const int tid  = threadIdx.x;
  const int lane = tid & 63;
  const int wid  = tid >> 6;
  const int wr = wid >> 1, wc = wid & 1;
  const int fr = lane & 15, fq = lane >> 4;
  const int row0 = blockIdx.x * 128, col0 = blockIdx.y * 128;
  const u16* ga = A + (size_t)row0 * K;
  const u16* gb = B + (size_t)col0 * K;
  f32x4 acc[4][4] = {};
  const int toff = tid * 16;

  for (int k0 = 0; k0 < K; k0 += 32) {
#pragma unroll
    for (int i = 0; i < 2; ++i) {
      int off = i * 4096 + toff;
      int rr  = off >> 6;
      int cb  = off & 63;
      __builtin_amdgcn_global_load_lds(
          (const __attribute__((address_space(1))) void*)((const char*)(ga + (size_t)rr * K + k0) + cb),
          (__attribute__((address_space(3))) void*)((char*)lds_a + off), 16, 0, 0);
      __builtin_amdgcn_global_load_lds(
          (const __attribute__((address_space(1))) void*)((const char*)(gb + (size_t)rr * K + k0) + cb),
          (__attribute__((address_space(3))) void*)((char*)lds_b + off), 16, 0, 0);
    }
    __syncthreads();
    bf16x8 af[4], bfv[4];
#pragma unroll
    for (int m = 0; m < 4; ++m)
      af[m] = *(const bf16x8*)&lds_a[(wr * 64 + m * 16 + fr) * 32 + fq * 8];
#pragma unroll
    for (int n = 0; n < 4; ++n)
      bfv[n] = *(const bf16x8*)&lds_b[(wc * 64 + n * 16 + fr) * 32 + fq * 8];
#pragma unroll
    for (int m = 0; m < 4; ++m)
#pragma unroll
      for (int n = 0; n < 4; ++n)
        acc[m][n] = __builtin_amdgcn_mfma_f32_16x16x32_bf16(af[m], bfv[n], acc[m][n], 0, 0, 0);
    __syncthreads();
  }

#pragma unroll
  for (int m = 0; m < 4; ++m)
#pragma unroll
    for (int n = 0; n < 4; ++n) {
      int row = row0 + wr * 64 + m * 16 + fq * 4;
      int col = col0 + wc * 64 + n * 16 + fr;
#pragma unroll
      for (int r = 0; r < 4; ++r)
        stor(C, (size_t)(row + r) * N + col, acc[m][n][r]);
    }
}

// ---------------------------------------------------------------------------
// RoPE in-place on q,k parts of qkv. Q pre-scaled by QSCALE.
// ---------------------------------------------------------------------------
__global__ void rope_qk(u16* qkv) {
  int idx = blockIdx.x * blockDim.x + threadIdx.x;
  int i4 = idx & 15;
  int h  = (idx >> 4) & 15;
  int t  = (idx >> 8) & 1;
  int s  = idx >> 9;
  u16* p = qkv + (size_t)s * 6144 + t * 2048 + h * 128 + i4 * 8;
  const float post = t ? 1.0f : QSCALE;
  u16x8 v = *(const u16x8*)p;
  u16x8 w;
#pragma unroll
  for (int j = 0; j < 4; ++j) {
    int i = i4 * 4 + j;
    float inv = exp2f(-(float)i * 0.2076205059304601f);  // 10000^(-i/64)
    float ang = (float)s * inv;
    float sn, cs;
    sincosf(ang, &sn, &cs);
    float e = bf2f(v[2 * j]);
    float o = bf2f(v[2 * j + 1]);
    w[2 * j]     = f2bf((e * cs - o * sn) * post);
    w[2 * j + 1] = f2bf((e * sn + o * cs) * post);
  }
  *(u16x8*)p = w;
}

// ---------------------------------------------------------------------------
// Repack V into per-(head, kv-tile) contiguous 8KB tiles, transposed and
// XOR-swizzled: vt2[(h*64+t)*4096 + d*32 + swz(d, j)], swz: 16B-chunk
// (j>>3) stored at chunk (j>>3)^(d&3). Staging then copies linearly; LDS
// reads apply the same XOR -> ~conflict-free.
// ---------------------------------------------------------------------------
__global__ void repack_v(const u16* __restrict__ qkv, u16* __restrict__ vt2) {
  __shared__ u16 tile[32][33];
  int s0 = blockIdx.x * 32, c0 = blockIdx.y * 32;
  int tx = threadIdx.x & 31, ty = threadIdx.x >> 5;  // 32 x 8
#pragma unroll
  for (int i = ty; i < 32; i += 8)
    tile[i][tx] = qkv[(size_t)(s0 + i) * 6144 + 4096 + c0 + tx];
  __syncthreads();
  int t = s0 >> 5;
#pragma unroll
  for (int i = ty; i < 32; i += 8) {
    int col = c0 + i;                 // h*128 + d
    int h = col >> 7, d = col & 127;
    size_t off = ((size_t)(h * 64 + t)) * 4096 + d * 32
               + ((((tx >> 3) ^ (d & 3)) << 3) | (tx & 7));
    vt2[off] = tile[tx][i];
  }
}

// ---------------------------------------------------------------------------
// Causal flash attention: paired split-KV + per-wave coalesced LDS staging.
// Block = 512 thr (8 waves) = 2 q-tiles (pair bp, 63-bp) x 4 kv-split waves.
// grid = (32, 16) remapped so each XCD handles 2 heads (L2 locality).
// Per iter: K staged from qkv (chunk-XOR source), V staged from vt2 (linear);
// software-pipelined: stage(t+4) issued after ds_reads of t retire.
// LDS: 8 waves x 16KB stage buffers; Obuf aliases them post-barrier.
// ---------------------------------------------------------------------------
__global__ __launch_bounds__(512, 2)
void attn_fwd(const u16* __restrict__ qkv, const u16* __restrict__ vt2,
              u16* __restrict__ ao) {
  const int f    = blockIdx.y * 32 + blockIdx.x;   // dispatch order (x-major)
  const int h    = ((f & 7) << 1) | ((f >> 3) & 1);  // 2 heads per XCD
  const int bp   = f >> 4;                          // pair index 0..31
  const int tid  = threadIdx.x;
  const int lane = tid & 63;
  const int wid  = tid >> 6;       // 0..7
  const int qsel = wid >> 2;
  const int ksel = wid & 3;
  const int l31  = lane & 31;
  const int hh   = lane >> 5;
  const int tile = qsel ? 63 - bp : bp;
  const int q0 = tile * 32;

  __shared__ __align__(16) char smem[131072];   // 8 waves x (K 8KB + V 8KB)
  __shared__ float mls[2][4][32][2];
  char* bufK = smem + wid * 16384;
  char* bufV = bufK + 8192;
  float (*Obuf)[32][128] = (float(*)[32][128])smem;  // alias; used after barrier

  const char* qkvB = (const char*)qkv;
  const char* vtB  = (const char*)vt2;
  const u16*  Qb   = qkv + h * 128;

  // hoisted Q fragments (pre-scaled by QSCALE in rope)
  const size_t qrow = (size_t)(q0 + l31) * 6144;
  bf16x8 qf[8];
#pragma unroll
  for (int s = 0; s < 8; ++s)
    qf[s] = *(const bf16x8*)&Qb[qrow + s * 16 + hh * 8];

  f32x16 oacc[4] = {};              // q=(r&3)+8*(r>>2)+4*hh, d=32c+l31
  float M = -1e30f, L = 0.f;

  const int krow4 = lane >> 4;      // 0..3
  const int kch   = lane & 15;

#define STAGE(T)                                                                \
  {                                                                             \
    const int kv0_ = (T) * 32;                                                  \
    _Pragma("unroll")                                                           \
    for (int k = 0; k < 8; ++k) {                                               \
      int row = k * 4 + krow4;                                                  \
      int ch  = kch ^ (row & 7);                                                \
      const char* src = qkvB + (size_t)(kv0_ + row) * 12288 + 4096 + h * 256 + ch * 16; \
      __builtin_amdgcn_global_load_lds(                                         \
          (const __attribute__((address_space(1))) void*)src,                   \
          (__attribute__((address_space(3))) void*)(bufK + k * 1024 + lane * 16), 16, 0, 0); \
    }                                                                           \
    const char* vsrc = vtB + ((size_t)(h * 64 + (T))) * 8192;                   \
    _Pragma("unroll")                                                           \
    for (int k = 0; k < 8; ++k)                                                 \
      __builtin_amdgcn_global_load_lds(                                         \
          (const __attribute__((address_space(1))) void*)(vsrc + k * 1024 + lane * 16), \
          (__attribute__((address_space(3))) void*)(bufV + k * 1024 + lane * 16), 16, 0, 0); \
  }

  if (ksel <= tile) STAGE(ksel);

  for (int t = ksel; t <= tile; t += 4) {
    asm volatile("s_waitcnt vmcnt(0)" ::: "memory");
    __builtin_amdgcn_sched_barrier(0);

    // LDS -> register fragments (XOR-swizzled reads)
    bf16x8 kf[8];
#pragma unroll
    for (int s = 0; s < 8; ++s)
      kf[s] = *(const bf16x8*)(bufK + l31 * 256 + (((s * 2 + hh) ^ (l31 & 7)) * 16));
    bf16x8 vf[4][2];
#pragma unroll
    for (int c = 0; c < 4; ++c)
#pragma unroll
      for (int tt = 0; tt < 2; ++tt)
        vf[c][tt] = *(const bf16x8*)(bufV + (32 * c + l31) * 64 + (((tt * 2 + hh) ^ (l31 & 3)) * 16));
    asm volatile("s_waitcnt lgkmcnt(0)" ::: "memory");
    __builtin_amdgcn_sched_barrier(0);

    if (t + 4 <= tile) STAGE(t + 4);   // prefetch into same buf (reads retired)
    __builtin_amdgcn_sched_barrier(0);

    // QK^T swapped: S[kv][q], q = l31
    f32x16 sc = {};
    __builtin_amdgcn_s_setprio(1);
#pragma unroll
    for (int s = 0; s < 8; ++s)
      sc = __builtin_amdgcn_mfma_f32_32x32x16_bf16(kf[s], qf[s], sc, 0, 0, 0);
    __builtin_amdgcn_s_setprio(0);

    if (t == tile) {
#pragma unroll
      for (int r = 0; r < 16; ++r) {
        int kv = (r & 3) + 8 * (r >> 2) + 4 * hh;
        if (kv > l31) sc[r] = -1e30f;
      }
    }

    // per-lane online softmax, T13 defer-max
    float pm = fmaxf(fmaxf(fmaxf(sc[0], sc[1]), fmaxf(sc[2], sc[3])),
                     fmaxf(fmaxf(sc[4], sc[5]), fmaxf(sc[6], sc[7])));
    float pm2 = fmaxf(fmaxf(fmaxf(sc[8], sc[9]), fmaxf(sc[10], sc[11])),
                      fmaxf(fmaxf(sc[12], sc[13]), fmaxf(sc[14], sc[15])));
    pm = fmaxf(pm, pm2);
    pm = fmaxf(pm, __shfl_xor(pm, 32, 64));

    bool defer = (pm <= M + 8.0f);
    if (!__all(defer)) {
      float Mn = fmaxf(M, pm);
      float corr = exp2f(M - Mn);
      M = Mn;
      L *= corr;
#pragma unroll
      for (int r = 0; r < 16; ++r) {
        float cr = __shfl(corr, (r & 3) + 8 * (r >> 2) + 4 * hh, 64);
#pragma unroll
        for (int c = 0; c < 4; ++c) oacc[c][r] *= cr;
      }
    }

#pragma unroll
    for (int r = 0; r < 16; ++r) sc[r] = exp2f(sc[r] - M);
    float rs = ((sc[0] + sc[1]) + (sc[2] + sc[3])) + ((sc[4] + sc[5]) + (sc[6] + sc[7]))
             + ((sc[8] + sc[9]) + (sc[10] + sc[11])) + ((sc[12] + sc[13]) + (sc[14] + sc[15]));
    rs += __shfl_xor(rs, 32, 64);
    L += rs;

    // pack P into PV A-frags and accumulate O
#pragma unroll
    for (int tt = 0; tt < 2; ++tt) {
      unsigned A0 = cvtpk(sc[8 * tt + 0], sc[8 * tt + 1]);
      unsigned A1 = cvtpk(sc[8 * tt + 2], sc[8 * tt + 3]);
      unsigned B0 = cvtpk(sc[8 * tt + 4], sc[8 * tt + 5]);
      unsigned B1 = cvtpk(sc[8 * tt + 6], sc[8 * tt + 7]);
      plswap(A0, B0);
      plswap(A1, B1);
      union { unsigned w[4]; bf16x8 v; } pa;
      pa.w[0] = A0; pa.w[1] = A1; pa.w[2] = B0; pa.w[3] = B1;
      __builtin_amdgcn_s_setprio(1);
#pragma unroll
      for (int c = 0; c < 4; ++c)
        oacc[c] = __builtin_amdgcn_mfma_f32_32x32x16_bf16(pa.v, vf[c][tt], oacc[c], 0, 0, 0);
      __builtin_amdgcn_s_setprio(0);
    }
  }
#undef STAGE

  // ---- flash merge across the 4 kv-split waves of each q-tile ----
  if (hh == 0) { mls[qsel][ksel][l31][0] = M; mls[qsel][ksel][l31][1] = L; }
  __syncthreads();   // all staging consumed; Obuf aliasing becomes safe

  for (int w = 0; w < 4; ++w) {
    if (ksel == w) {
#pragma unroll
      for (int r = 0; r < 16; ++r) {
        int q = (r & 3) + 8 * (r >> 2) + 4 * hh;
        float m_own = mls[qsel][ksel][q][0];
        float Mg = fmaxf(fmaxf(mls[qsel][0][q][0], mls[qsel][1][q][0]),
                         fmaxf(mls[qsel][2][q][0], mls[qsel][3][q][0]));
        float s = exp2f(m_own - Mg);
#pragma unroll
        for (int c = 0; c < 4; ++c) {
          float v = oacc[c][r] * s;
          if (w == 0) Obuf[qsel][q][32 * c + l31] = v;
          else        Obuf[qsel][q][32 * c + l31] += v;
        }
      }
    }
    __syncthreads();
  }

  // write-out: wave (qsel,ksel) normalizes+stores rows ksel*8 .. ksel*8+7
#pragma unroll
  for (int rr = 0; rr < 8; ++rr) {
    int row = ksel * 8 + rr;
    float Mg = fmaxf(fmaxf(mls[qsel][0][row][0], mls[qsel][1][row][0]),
                     fmaxf(mls[qsel][2][row][0], mls[qsel][3][row][0]));
    float lt = 0.f;
#pragma unroll
    for (int w2 = 0; w2 < 4; ++w2)
      lt += exp2f(mls[qsel][w2][row][0] - Mg) * mls[qsel][w2][row][1];
    float inv = 1.0f / lt;
    float v0 = Obuf[qsel][row][lane * 2]     * inv;
    float v1 = Obuf[qsel][row][lane * 2 + 1] * inv;
    unsigned pack = (unsigned)f2bf(v0) | ((unsigned)f2bf(v1) << 16);
    *(unsigned*)&ao[(size_t)(q0 + row) * 2048 + h * 128 + lane * 2] = pack;
  }
}

// ---------------------------------------------------------------------------
extern "C" void kernel_launch(void* const* d_in, const int* in_sizes, int n_in,
                              void* d_out, int out_size, void* d_ws, size_t ws_size,
                              hipStream_t stream) {
  const float* x     = (const float*)d_in[0];   // 2048 x 2048 f32
  const float* w_qkv = (const float*)d_in[1];   // 6144 x 2048 f32
  const float* w_out = (const float*)d_in[2];   // 2048 x 2048 f32
  float* out = (float*)d_out;                   // 2048 x 2048 f32
  const int S = 2048, H = 2048, O3 = 6144;

  // workspace (u16 elems), peak 58.8 MB with aliasing:
  u16* qkv     = (u16*)d_ws;                    // S*O3 = 25.2 MB
  u16* x_bf    = qkv + (size_t)S * O3;          //  8.4 MB
  u16* wqkv_bf = x_bf + (size_t)S * H;          // 25.2 MB
  u16* ao      = x_bf;                          // alias (x_bf dead after GEMM1)
  u16* vt2     = wqkv_bf;                       // alias (wqkv_bf dead after GEMM1)
  u16* wout_bf = wqkv_bf + (size_t)H * S;       // alias, fits in wqkv_bf region

  // 1. convert inputs to bf16
  conv_f32_bf16<<<(S * H) / 1024, 256, 0, stream>>>(x, x_bf);
  conv_f32_bf16<<<(O3 * H) / 1024, 256, 0, stream>>>(w_qkv, wqkv_bf);
  // 2. qkv = x @ w_qkv^T   (M=2048, N=6144, K=2048)
  gemm_bt<u16><<<dim3(S / 128, O3 / 128), 256, 0, stream>>>(x_bf, wqkv_bf, qkv, S, O3, H);
  // 3. RoPE on q,k in place (q pre-scaled by QSCALE)
  rope_qk<<<(S * 2 * 16 * 16) / 256, 256, 0, stream>>>(qkv);
  // 4. repack V into swizzled per-(h,t) tiles
  repack_v<<<dim3(S / 32, H / 32), 256, 0, stream>>>(qkv, vt2);
  // 5. convert w_out
  conv_f32_bf16<<<(S * H) / 1024, 256, 0, stream>>>(w_out, wout_bf);
  // 6. causal flash attention (paired split-KV, LDS-staged) -> ao
  attn_fwd<<<dim3(32, 16), 512, 0, stream>>>(qkv, vt2, ao);
  // 7. out = ao @ w_out^T  (M=2048, N=2048, K=2048), f32 store
  gemm_bt<float><<<dim3(S / 128, H / 128), 256, 0, stream>>>(ao, wout_bf, out, S, H, H);
}